// Round 2
// baseline (335.684 us; speedup 1.0000x reference)
//
#include <hip/hip_runtime.h>

typedef _Float16 f16;
typedef _Float16 f16x4 __attribute__((ext_vector_type(4)));
typedef _Float16 f16x8 __attribute__((ext_vector_type(8)));
typedef float    f32x4 __attribute__((ext_vector_type(4)));

#define MFMA16(a,b,c) __builtin_amdgcn_mfma_f32_16x16x32_f16((a),(b),(c),0,0,0)

#define LATENT 64
#define HIDDEN 128

// A-fragment of W[out][K] for out-tile `tile`, k-chunk kf (32 wide).
// mfma_f32_16x16x32_f16 A layout: row = lane%16, k = kf*32 + 8*(lane/16)+j
__device__ __forceinline__ f16x8 load_afrag(const float* __restrict__ W, int K,
                                            int tile, int kf, int lane) {
  const int row = tile * 16 + (lane & 15);
  const int k0  = kf * 32 + (lane >> 4) * 8;
  const float* p = W + row * K + k0;
  f16x8 r;
#pragma unroll
  for (int j = 0; j < 8; ++j) r[j] = (f16)p[j];
  return r;
}

// B-fragment from LDS activation tile [16 rows][dims] f16, XOR-swizzled rows.
__device__ __forceinline__ f16x8 bfrag(const f16* buf, int rowb, int k0, int lane) {
  const int b  = lane & 15;
  const int kk = k0 + (lane >> 4) * 8;
  const int off = b * rowb + ((kk * 2) ^ ((b & 7) << 4));
  return *(const f16x8*)((const char*)buf + off);
}

// Write one D-tile (f32x4 -> f16x4) into an activation buffer, same swizzle.
__device__ __forceinline__ void dwrite(f16* buf, int rowb, int dbase, f32x4 v, int lane) {
  const int b = lane & 15;
  f16x4 h;
#pragma unroll
  for (int i = 0; i < 4; ++i) h[i] = (f16)v[i];
  const int off = b * rowb + ((dbase * 2) ^ ((b & 7) << 4));
  *(f16x4*)((char*)buf + off) = h;
}

__device__ __forceinline__ f32x4 elu4(f32x4 v) {
#pragma unroll
  for (int i = 0; i < 4; ++i) v[i] = v[i] > 0.f ? v[i] : (__expf(v[i]) - 1.f);
  return v;
}

// Raw barrier: no vmcnt drain (decoder path — global stores stay in flight).
__device__ __forceinline__ void bar_raw() {
  __builtin_amdgcn_s_barrier();
  __builtin_amdgcn_sched_barrier(0);
}

__global__ __launch_bounds__(512, 2)
void node_rk4_kernel(const float* __restrict__ z0,   const float* __restrict__ tg,
                     const float* __restrict__ fc1w, const float* __restrict__ fc1b,
                     const float* __restrict__ fc2w, const float* __restrict__ fc2b,
                     const float* __restrict__ fc3w, const float* __restrict__ fc3b,
                     const float* __restrict__ l2hw, const float* __restrict__ l2hb,
                     const float* __restrict__ h2ow, const float* __restrict__ h2ob,
                     float* __restrict__ out, int Btot, int T) {
  __shared__ __align__(16) f16 zhist[4][16 * 64];  // z_s ring (decoder lags <=3 steps)
  __shared__ __align__(16) f16 xbuf[16 * 64];      // k2/k3/k4 inputs
  __shared__ __align__(16) f16 h1buf[16 * 128];    // integrator hidden1
  __shared__ __align__(16) f16 h2buf[16 * 128];    // integrator hidden2
  __shared__ __align__(16) f16 dch1[16 * 128];     // decoder hidden (1 active wave/step)

  const int tid  = threadIdx.x;
  const int lane = tid & 63;
  const int wv   = tid >> 6;   // 0..7
  const int iw   = wv & 3;     // role index within group
  const int grp  = lane >> 4;
  const int bcol = lane & 15;
  const int row0 = blockIdx.x * 16;

  if (wv < 4) {
    // ======================= integrator (waves 0-3) =======================
    // wave iw owns hidden dims [32iw,32iw+32) and latent dims [16iw,16iw+16)
    f16x8 a1[2][2], a2[2][4], a3[4];
    f32x4 b1[2], b2[2], b3;
#pragma unroll
    for (int ot = 0; ot < 2; ++ot) {
#pragma unroll
      for (int kf = 0; kf < 2; ++kf) a1[ot][kf] = load_afrag(fc1w, 64, 2 * iw + ot, kf, lane);
#pragma unroll
      for (int kf = 0; kf < 4; ++kf) a2[ot][kf] = load_afrag(fc2w, 128, 2 * iw + ot, kf, lane);
      const int d = (2 * iw + ot) * 16 + grp * 4;
      b1[ot] = *(const f32x4*)(fc1b + d);
      b2[ot] = *(const f32x4*)(fc2b + d);
    }
#pragma unroll
    for (int kf = 0; kf < 4; ++kf) a3[kf] = load_afrag(fc3w, 128, iw, kf, lane);
    const int dz = iw * 16 + grp * 4;
    b3 = *(const f32x4*)(fc3b + dz);

    f32x4 z = *(const f32x4*)(z0 + (size_t)(row0 + bcol) * LATENT + dz);

    // f on buffer xb; 2 internal barriers, none at the end
    auto feval = [&](const f16* xb) -> f32x4 {
      const f16x8 v0 = bfrag(xb, 128, 0, lane);
      const f16x8 v1 = bfrag(xb, 128, 32, lane);
#pragma unroll
      for (int ot = 0; ot < 2; ++ot) {
        f32x4 d = {0.f, 0.f, 0.f, 0.f};
        d = MFMA16(a1[ot][0], v0, d);
        d = MFMA16(a1[ot][1], v1, d);
        d += b1[ot];
        d = elu4(d);
        dwrite(h1buf, 256, (2 * iw + ot) * 16 + grp * 4, d, lane);
      }
      __syncthreads();
      f16x8 h[4];
#pragma unroll
      for (int kf = 0; kf < 4; ++kf) h[kf] = bfrag(h1buf, 256, kf * 32, lane);
#pragma unroll
      for (int ot = 0; ot < 2; ++ot) {
        f32x4 c0 = {0.f, 0.f, 0.f, 0.f}, c1 = {0.f, 0.f, 0.f, 0.f};
        c0 = MFMA16(a2[ot][0], h[0], c0);
        c0 = MFMA16(a2[ot][1], h[1], c0);
        c1 = MFMA16(a2[ot][2], h[2], c1);
        c1 = MFMA16(a2[ot][3], h[3], c1);
        f32x4 d = c0 + c1 + b2[ot];
        d = elu4(d);
        dwrite(h2buf, 256, (2 * iw + ot) * 16 + grp * 4, d, lane);
      }
      __syncthreads();
      f16x8 g[4];
#pragma unroll
      for (int kf = 0; kf < 4; ++kf) g[kf] = bfrag(h2buf, 256, kf * 32, lane);
      f32x4 c0 = {0.f, 0.f, 0.f, 0.f}, c1 = {0.f, 0.f, 0.f, 0.f};
      c0 = MFMA16(a3[0], g[0], c0);
      c0 = MFMA16(a3[1], g[1], c0);
      c1 = MFMA16(a3[2], g[2], c1);
      c1 = MFMA16(a3[3], g[3], c1);
      return c0 + c1 + b3;
    };

    for (int s = 0; s < T; ++s) {
      dwrite(zhist[s & 3], 128, dz, z, lane);  // publish z_s (also the k1 input)
      __syncthreads();                         // BAR 1 — decoder picks it up
      if (s == T - 1) break;
      const float dt = tg[s + 1] - tg[s];

      f32x4 k = feval(zhist[s & 3]);           // k1   (BAR 2,3)
      f32x4 acc = k, xs;
#pragma unroll
      for (int i = 0; i < 4; ++i) xs[i] = z[i] + 0.5f * dt * k[i];
      dwrite(xbuf, 128, dz, xs, lane);
      __syncthreads();                         // BAR 4
      k = feval(xbuf);                         // k2   (BAR 5,6)
#pragma unroll
      for (int i = 0; i < 4; ++i) { acc[i] += 2.f * k[i]; xs[i] = z[i] + 0.5f * dt * k[i]; }
      dwrite(xbuf, 128, dz, xs, lane);
      __syncthreads();                         // BAR 7
      k = feval(xbuf);                         // k3   (BAR 8,9)
#pragma unroll
      for (int i = 0; i < 4; ++i) { acc[i] += 2.f * k[i]; xs[i] = z[i] + dt * k[i]; }
      dwrite(xbuf, 128, dz, xs, lane);
      __syncthreads();                         // BAR 10
      k = feval(xbuf);                         // k4   (BAR 11,12)
#pragma unroll
      for (int i = 0; i < 4; ++i) z[i] += (dt / 6.f) * (acc[i] + k[i]);
    }
  } else {
    // ======================= decoder (waves 4-7) =======================
    // wave iw decodes steps s with s%4 == iw, fully (no internal barriers)
    f16x8 aL[8][2], aO[4][4];
    f32x4 bLr[8], bOr[4];
#pragma unroll
    for (int ot = 0; ot < 8; ++ot) {
      aL[ot][0] = load_afrag(l2hw, 64, ot, 0, lane);
      aL[ot][1] = load_afrag(l2hw, 64, ot, 1, lane);
      bLr[ot] = *(const f32x4*)(l2hb + ot * 16 + grp * 4);
    }
#pragma unroll
    for (int t = 0; t < 4; ++t) {
#pragma unroll
      for (int kf = 0; kf < 4; ++kf) aO[t][kf] = load_afrag(h2ow, 128, t, kf, lane);
      bOr[t] = *(const f32x4*)(h2ob + t * 16 + grp * 4);
    }

    for (int s = 0; s < T; ++s) {
      bar_raw();                               // BAR 1 — z_s published
      if ((s & 3) == iw) {
        const f16* zb = zhist[s & 3];
        const f16x8 zf0 = bfrag(zb, 128, 0, lane);
        const f16x8 zf1 = bfrag(zb, 128, 32, lane);
#pragma unroll
        for (int ot = 0; ot < 8; ++ot) {
          f32x4 d = {0.f, 0.f, 0.f, 0.f};
          d = MFMA16(aL[ot][0], zf0, d);
          d = MFMA16(aL[ot][1], zf1, d);
          d += bLr[ot];
#pragma unroll
          for (int i = 0; i < 4; ++i) d[i] = fmaxf(d[i], 0.f);
          dwrite(dch1, 256, ot * 16 + grp * 4, d, lane);
        }
        f16x8 h[4];
#pragma unroll
        for (int kf = 0; kf < 4; ++kf) h[kf] = bfrag(dch1, 256, kf * 32, lane);
#pragma unroll
        for (int t = 0; t < 4; ++t) {
          f32x4 c0 = {0.f, 0.f, 0.f, 0.f}, c1 = {0.f, 0.f, 0.f, 0.f};
          c0 = MFMA16(aO[t][0], h[0], c0);
          c0 = MFMA16(aO[t][1], h[1], c0);
          c1 = MFMA16(aO[t][2], h[2], c1);
          c1 = MFMA16(aO[t][3], h[3], c1);
          f32x4 o = c0 + c1 + bOr[t];
          // coalesced: 4 lanes (grp 0..3) cover each row's 64B segment
          *(f32x4*)(out + ((size_t)s * Btot + row0 + bcol) * LATENT + t * 16 + grp * 4) = o;
        }
      }
      if (s < T - 1) {
#pragma unroll 1
        for (int b2 = 0; b2 < 11; ++b2) bar_raw();  // match BAR 2..12
      }
    }
  }
}

extern "C" void kernel_launch(void* const* d_in, const int* in_sizes, int n_in,
                              void* d_out, int out_size, void* d_ws, size_t ws_size,
                              hipStream_t stream) {
  const float* z0   = (const float*)d_in[0];
  const float* tg   = (const float*)d_in[1];
  const float* fc1w = (const float*)d_in[2];
  const float* fc1b = (const float*)d_in[3];
  const float* fc2w = (const float*)d_in[4];
  const float* fc2b = (const float*)d_in[5];
  const float* fc3w = (const float*)d_in[6];
  const float* fc3b = (const float*)d_in[7];
  const float* l2hw = (const float*)d_in[8];
  const float* l2hb = (const float*)d_in[9];
  const float* h2ow = (const float*)d_in[10];
  const float* h2ob = (const float*)d_in[11];
  float* out = (float*)d_out;

  const int Btot = in_sizes[0] / LATENT;  // 4096
  const int T    = in_sizes[1];           // 100

  dim3 grid(Btot / 16), block(512);
  node_rk4_kernel<<<grid, block, 0, stream>>>(z0, tg, fc1w, fc1b, fc2w, fc2b,
                                              fc3w, fc3b, l2hw, l2hb, h2ow, h2ob,
                                              out, Btot, T);
}